// Round 1
// baseline (892.183 us; speedup 1.0000x reference)
//
#include <hip/hip_runtime.h>

// ---------------- problem dims (fixed by setup_inputs) ----------------
#define B_    256
#define A_    128
#define D_    16
#define FA_   64
#define FB_   32
#define NB_   256
#define FP_   256
#define NRA   32768      // B_*A_   (atom rows)
#define NRN   524288     // B_*A_*D_ (neighbor rows)
#define NRV   65536      // B_*NB_  (bond rows)
#define OUT_NEI 8388608  // NRA*FP_

// ---------------- ws layout (float offsets) ----------------
// U_nei: NRA*FP_ ; V_nei: NRV*FP_ ; stats: 1024 ; params: 1024
#define WS_U    0
#define WS_V    8388608
#define WS_STAT 25165824
#define WS_PAR  (WS_STAT + 1024)
#define WS_NEED ((size_t)(WS_PAR + 1024) * 4)
// stat layout: [sumA 256][sqA 256][sumN 256][sqN 256]
// par  layout: [sA 256][uA 256][sN 256][uN 256]

#define DEV_INLINE __device__ __forceinline__
DEV_INLINE float lrelu(float x) { return x >= 0.f ? x : 0.01f * x; }

// =====================================================================
// K1: three dense f32 GEMMs in one kernel.
//   G0: U_atom = af(32768x64) @ atom_W(256x64)^T          -> d_out[0:NRA*256]
//   G1: U_nei  = af(32768x64) @ nei_W[:, 0:64]^T          -> ws[WS_U]
//   G2: V_nei  = bf(65536x32) @ nei_W[:, 64:96]^T         -> ws[WS_V]
// tile 128 rows x 128 cols, 256 thr, 8x8 per thread, K-chunks of 32.
// =====================================================================
__global__ __launch_bounds__(256) void k_gemm3(const float* __restrict__ af,
                                               const float* __restrict__ bf,
                                               const float* __restrict__ atom_W,
                                               const float* __restrict__ nei_W,
                                               float* __restrict__ out,
                                               float* __restrict__ ws) {
    __shared__ float Xs[128][36];   // rows x k-chunk (pad 36: bank-clean, 16B-aligned)
    __shared__ float Wt[32][128];   // k x cols (transposed W)

    const int bid = blockIdx.x;
    const int cb  = bid & 1;
    const int q   = bid >> 1;

    const float* Xp; int xstr, nck; const float* Wp; int wstr, wofs; float* outp;
    int rb;
    if (q < 256)      { Xp = af; xstr = 64; nck = 2; Wp = atom_W; wstr = 64; wofs = 0;  outp = out;         rb = q;       }
    else if (q < 512) { Xp = af; xstr = 64; nck = 2; Wp = nei_W;  wstr = 96; wofs = 0;  outp = ws + WS_U;   rb = q - 256; }
    else              { Xp = bf; xstr = 32; nck = 1; Wp = nei_W;  wstr = 96; wofs = 64; outp = ws + WS_V;   rb = q - 512; }
    const int row0 = rb * 128;
    const int c0   = cb * 128;
    const int tid  = threadIdx.x;

    float acc[8][8];
#pragma unroll
    for (int i = 0; i < 8; ++i)
#pragma unroll
        for (int j = 0; j < 8; ++j) acc[i][j] = 0.f;

    const int sr  = tid >> 1, st  = tid & 1;   // X staging: row, 16-float half
    const int wc  = tid >> 1, wt2 = tid & 1;   // W staging: col (0..127), half
    const int ty  = tid >> 4, tx  = tid & 15;

    for (int ck = 0; ck < nck; ++ck) {
        const int k0 = ck * 32;
        const float* xg = Xp + (row0 + sr) * xstr + k0 + st * 16;
        float4 xv0 = *(const float4*)(xg + 0);
        float4 xv1 = *(const float4*)(xg + 4);
        float4 xv2 = *(const float4*)(xg + 8);
        float4 xv3 = *(const float4*)(xg + 12);
        const float* wg = Wp + (c0 + wc) * wstr + wofs + k0 + wt2 * 16;
        float4 wv0 = *(const float4*)(wg + 0);
        float4 wv1 = *(const float4*)(wg + 4);
        float4 wv2 = *(const float4*)(wg + 8);
        float4 wv3 = *(const float4*)(wg + 12);

        __syncthreads();  // previous chunk's compute done
        *(float4*)&Xs[sr][st * 16 + 0]  = xv0;
        *(float4*)&Xs[sr][st * 16 + 4]  = xv1;
        *(float4*)&Xs[sr][st * 16 + 8]  = xv2;
        *(float4*)&Xs[sr][st * 16 + 12] = xv3;
        {
            const int kb = wt2 * 16;
            Wt[kb + 0][wc] = wv0.x; Wt[kb + 1][wc] = wv0.y; Wt[kb + 2][wc] = wv0.z; Wt[kb + 3][wc] = wv0.w;
            Wt[kb + 4][wc] = wv1.x; Wt[kb + 5][wc] = wv1.y; Wt[kb + 6][wc] = wv1.z; Wt[kb + 7][wc] = wv1.w;
            Wt[kb + 8][wc] = wv2.x; Wt[kb + 9][wc] = wv2.y; Wt[kb +10][wc] = wv2.z; Wt[kb +11][wc] = wv2.w;
            Wt[kb +12][wc] = wv3.x; Wt[kb +13][wc] = wv3.y; Wt[kb +14][wc] = wv3.z; Wt[kb +15][wc] = wv3.w;
        }
        __syncthreads();

#pragma unroll 2
        for (int kq = 0; kq < 8; ++kq) {
            float4 xr[8];
#pragma unroll
            for (int i = 0; i < 8; ++i)
                xr[i] = *(const float4*)&Xs[ty + 16 * i][kq * 4];
            float4 wa[4], wb[4];
#pragma unroll
            for (int kk = 0; kk < 4; ++kk) {
                wa[kk] = *(const float4*)&Wt[kq * 4 + kk][tx * 4];
                wb[kk] = *(const float4*)&Wt[kq * 4 + kk][64 + tx * 4];
            }
#pragma unroll
            for (int i = 0; i < 8; ++i) {
#pragma unroll
                for (int kk = 0; kk < 4; ++kk) {
                    const float xs = (kk == 0) ? xr[i].x : (kk == 1) ? xr[i].y : (kk == 2) ? xr[i].z : xr[i].w;
                    acc[i][0] = fmaf(xs, wa[kk].x, acc[i][0]);
                    acc[i][1] = fmaf(xs, wa[kk].y, acc[i][1]);
                    acc[i][2] = fmaf(xs, wa[kk].z, acc[i][2]);
                    acc[i][3] = fmaf(xs, wa[kk].w, acc[i][3]);
                    acc[i][4] = fmaf(xs, wb[kk].x, acc[i][4]);
                    acc[i][5] = fmaf(xs, wb[kk].y, acc[i][5]);
                    acc[i][6] = fmaf(xs, wb[kk].z, acc[i][6]);
                    acc[i][7] = fmaf(xs, wb[kk].w, acc[i][7]);
                }
            }
        }
    }

#pragma unroll
    for (int i = 0; i < 8; ++i) {
        const int r = row0 + ty + 16 * i;
        float4 vA = { acc[i][0], acc[i][1], acc[i][2], acc[i][3] };
        float4 vB = { acc[i][4], acc[i][5], acc[i][6], acc[i][7] };
        *(float4*)(outp + r * 256 + c0 + tx * 4)      = vA;
        *(float4*)(outp + r * 256 + c0 + 64 + tx * 4) = vB;
    }
}

// =====================================================================
// K2: per-channel moments.
//  blocks [0,256): atom path, elementwise over U_atom (= d_out atom region)
//  blocks [256,1280): neighbor path, gather y = U[an] + V[bn]
// =====================================================================
__global__ __launch_bounds__(256) void k_stats(const float* __restrict__ uat,
                                               const int* __restrict__ anl,
                                               const int* __restrict__ bnl,
                                               const float* __restrict__ wsu,
                                               const float* __restrict__ wsv,
                                               float* __restrict__ stat) {
    const int blk = blockIdx.x;
    const int tid = threadIdx.x;
    if (blk < 256) {
        const int row0 = blk * 128;
        float sum = 0.f, sq = 0.f;
#pragma unroll 4
        for (int r = 0; r < 128; ++r) {
            float y = uat[(row0 + r) * 256 + tid];
            sum += y; sq = fmaf(y, y, sq);
        }
        atomicAdd(&stat[tid], sum);
        atomicAdd(&stat[256 + tid], sq);
    } else {
        __shared__ int sa[512], sb[512];
        const int nb2  = blk - 256;      // 0..1023
        const int row0 = nb2 * 512;
        sa[tid]       = anl[row0 + tid];
        sa[tid + 256] = anl[row0 + 256 + tid];
        sb[tid]       = bnl[row0 + tid];
        sb[tid + 256] = bnl[row0 + 256 + tid];
        __syncthreads();
        const int b = row0 >> 11;        // 512 rows stay within one batch (2048 rows/batch)
        const int baseU = (b << 7) * 256;
        const int baseV = (b << 8) * 256;
        float sum = 0.f, sq = 0.f;
#pragma unroll 4
        for (int r = 0; r < 512; ++r) {
            float u = wsu[baseU + sa[r] * 256 + tid];
            float v = wsv[baseV + sb[r] * 256 + tid];
            float y = u + v;
            sum += y; sq = fmaf(y, y, sq);
        }
        atomicAdd(&stat[512 + tid], sum);
        atomicAdd(&stat[768 + tid], sq);
    }
}

// =====================================================================
// K3: finalize per-channel affine: s = gamma/sqrt(var+eps), u = beta - mu*s
// (bias b cancels exactly through BatchNorm; never needed)
// =====================================================================
__global__ void k_finalize(const float* __restrict__ stat,
                           const float* __restrict__ ag, const float* __restrict__ ab,
                           const float* __restrict__ ng, const float* __restrict__ nbt,
                           float* __restrict__ par) {
    const int t = threadIdx.x;
    if (t < 256) {
        const float N = 32768.f;
        float mu  = stat[t] / N;
        float var = stat[256 + t] / N - mu * mu;
        float s   = ag[t] / sqrtf(var + 1e-6f);
        par[t]       = s;
        par[256 + t] = ab[t] - mu * s;
    } else {
        const int c = t - 256;
        const float N = 524288.f;
        float mu  = stat[512 + c] / N;
        float var = stat[768 + c] / N - mu * mu;
        float s   = ng[c] / sqrtf(var + 1e-6f);
        par[512 + c] = s;
        par[768 + c] = nbt[c] - mu * s;
    }
}

// =====================================================================
// K4: output pass.
//  blocks [0,256): atom region in-place affine+lrelu (float4)
//  blocks [256,2304): neighbor gather U[an]+V[bn] -> affine -> lrelu -> store
// =====================================================================
__global__ __launch_bounds__(256) void k_out(const int* __restrict__ anl,
                                             const int* __restrict__ bnl,
                                             const float* __restrict__ wsu,
                                             const float* __restrict__ wsv,
                                             const float* __restrict__ par,
                                             float* __restrict__ out) {
    const int blk = blockIdx.x;
    const int tid = threadIdx.x;
    if (blk < 256) {
        float4* o4 = (float4*)out;
        const float4* pS = (const float4*)(par);
        const float4* pU = (const float4*)(par + 256);
        const int c4 = tid & 63;         // (fi & 63) is invariant: strides are multiples of 64
        // careful: fi = blk*8192 + it*256 + tid -> fi&63 == tid&63
        float4 s = pS[c4], u = pU[c4];
        for (int it = 0; it < 32; ++it) {
            const int fi = blk * 8192 + it * 256 + tid;
            float4 y = o4[fi];
            float4 o;
            o.x = lrelu(fmaf(y.x, s.x, u.x));
            o.y = lrelu(fmaf(y.y, s.y, u.y));
            o.z = lrelu(fmaf(y.z, s.z, u.z));
            o.w = lrelu(fmaf(y.w, s.w, u.w));
            o4[fi] = o;
        }
    } else {
        const int nb2  = blk - 256;      // 0..2047
        const int lane = tid & 63;
        const int rr   = tid >> 6;
        const float4* pS = (const float4*)(par + 512);
        const float4* pU = (const float4*)(par + 768);
        const float4 s = pS[lane], u = pU[lane];
        const int row0 = nb2 * 256;
        const int b    = row0 >> 11;
        float4* onei = (float4*)(out + OUT_NEI);
        for (int it = 0; it < 64; ++it) {
            const int rg = row0 + it * 4 + rr;
            const int an = anl[rg];
            const int bn = bnl[rg];
            const float4* up = (const float4*)(wsu + ((b << 7) + an) * 256);
            const float4* vp = (const float4*)(wsv + ((b << 8) + bn) * 256);
            float4 u4 = up[lane];
            float4 v4 = vp[lane];
            float4 o;
            o.x = lrelu(fmaf(u4.x + v4.x, s.x, u.x));
            o.y = lrelu(fmaf(u4.y + v4.y, s.y, u.y));
            o.z = lrelu(fmaf(u4.z + v4.z, s.z, u.z));
            o.w = lrelu(fmaf(u4.w + v4.w, s.w, u.w));
            onei[rg * 64 + lane] = o;
        }
    }
}

// =====================================================================
// Fallback path (only if ws_size < WS_NEED): direct y + fused stats, then
// finalize, then in-place affine. Slow but correct; needs only 8KB ws.
// =====================================================================
__global__ __launch_bounds__(256) void k_fb_y(const float* __restrict__ af,
                                              const float* __restrict__ bf,
                                              const int* __restrict__ anl,
                                              const int* __restrict__ bnl,
                                              const float* __restrict__ atom_W,
                                              const float* __restrict__ nei_W,
                                              float* __restrict__ stat,
                                              float* __restrict__ out) {
    __shared__ float Xs[32][100];
    const int blk = blockIdx.x;
    const int tid = threadIdx.x;
    const bool isN = blk < 16384;
    const int row0 = isN ? blk * 32 : (blk - 16384) * 32;
    const int K    = isN ? 96 : 64;
    const float* W = isN ? nei_W : atom_W;

    const int r = tid >> 3, t = tid & 7;
    if (isN) {
        const int rg = row0 + r;
        const int b  = rg >> 11;
        const float4* ap = (const float4*)(af + ((b << 7) + anl[rg]) * 64);
        const float4* bp = (const float4*)(bf + ((b << 8) + bnl[rg]) * 32);
        *(float4*)&Xs[r][t * 4]      = ap[t];
        *(float4*)&Xs[r][32 + t * 4] = ap[t + 8];
        *(float4*)&Xs[r][64 + t * 4] = bp[t];
    } else {
        const float4* ap = (const float4*)(af + (row0 + r) * 64);
        *(float4*)&Xs[r][t * 4]      = ap[t];
        *(float4*)&Xs[r][32 + t * 4] = ap[t + 8];
    }
    __syncthreads();

    const int c = tid;
    const float* wr = W + c * K;
    float* outp = isN ? (out + OUT_NEI + row0 * 256) : (out + row0 * 256);
    float sum = 0.f, sq = 0.f;
    for (int rr2 = 0; rr2 < 32; ++rr2) {
        float y = 0.f;
        for (int k = 0; k < K; k += 4) {
            float4 x = *(float4*)&Xs[rr2][k];
            float4 w = *(const float4*)(wr + k);
            y = fmaf(x.x, w.x, y); y = fmaf(x.y, w.y, y);
            y = fmaf(x.z, w.z, y); y = fmaf(x.w, w.w, y);
        }
        sum += y; sq = fmaf(y, y, sq);
        outp[rr2 * 256 + c] = y;
    }
    atomicAdd(&stat[(isN ? 512 : 0) + c], sum);
    atomicAdd(&stat[(isN ? 768 : 256) + c], sq);
}

__global__ __launch_bounds__(256) void k_fb_apply(const float* __restrict__ par,
                                                  float* __restrict__ out) {
    const int idx0 = blockIdx.x * 256 + threadIdx.x;  // 524288 threads
    float4* o4 = (float4*)out;
    const int c4 = idx0 & 63;
    const float4 sA = ((const float4*)(par))[c4];
    const float4 uA = ((const float4*)(par + 256))[c4];
    const float4 sN = ((const float4*)(par + 512))[c4];
    const float4 uN = ((const float4*)(par + 768))[c4];
    for (int it = 0; it < 68; ++it) {
        const int fi = it * 524288 + idx0;
        const bool atom = fi < 2097152;
        const float4 s = atom ? sA : sN;
        const float4 u = atom ? uA : uN;
        float4 y = o4[fi];
        float4 o;
        o.x = lrelu(fmaf(y.x, s.x, u.x));
        o.y = lrelu(fmaf(y.y, s.y, u.y));
        o.z = lrelu(fmaf(y.z, s.z, u.z));
        o.w = lrelu(fmaf(y.w, s.w, u.w));
        o4[fi] = o;
    }
}

// =====================================================================
extern "C" void kernel_launch(void* const* d_in, const int* in_sizes, int n_in,
                              void* d_out, int out_size, void* d_ws, size_t ws_size,
                              hipStream_t stream) {
    const float* af  = (const float*)d_in[0];
    const float* bf  = (const float*)d_in[1];
    const int*   anl = (const int*)d_in[2];
    const int*   bnl = (const int*)d_in[3];
    const float* aW  = (const float*)d_in[4];
    // d_in[5] atom_b: cancels exactly through BatchNorm
    const float* ag  = (const float*)d_in[6];
    const float* ab  = (const float*)d_in[7];
    const float* nW  = (const float*)d_in[8];
    // d_in[9] nei_b: cancels exactly through BatchNorm
    const float* ng  = (const float*)d_in[10];
    const float* nbt = (const float*)d_in[11];
    float* out = (float*)d_out;
    float* ws  = (float*)d_ws;

    if (ws_size >= WS_NEED) {
        hipMemsetAsync(ws + WS_STAT, 0, 1024 * sizeof(float), stream);
        k_gemm3<<<2048, 256, 0, stream>>>(af, bf, aW, nW, out, ws);
        k_stats<<<1280, 256, 0, stream>>>(out, anl, bnl, ws + WS_U, ws + WS_V, ws + WS_STAT);
        k_finalize<<<1, 512, 0, stream>>>(ws + WS_STAT, ag, ab, ng, nbt, ws + WS_PAR);
        k_out<<<2304, 256, 0, stream>>>(anl, bnl, ws + WS_U, ws + WS_V, ws + WS_PAR, out);
    } else {
        // fallback: needs only 8KB of ws
        hipMemsetAsync(ws, 0, 1024 * sizeof(float), stream);
        k_fb_y<<<17408, 256, 0, stream>>>(af, bf, anl, bnl, aW, nW, ws, out);
        k_finalize<<<1, 512, 0, stream>>>(ws, ag, ab, ng, nbt, ws + 1024);
        k_fb_apply<<<2048, 256, 0, stream>>>(ws + 1024, out);
    }
}